// Round 1
// baseline (2609.637 us; speedup 1.0000x reference)
//
#include <hip/hip_runtime.h>

#define NN 50000
#define DD 64
#define EE 800000
#define BN_EPS 1e-5f
#define NEG 0.01f

typedef float4 f4;

// ---- init embeddings: 4 copies of features into d_out ----
__global__ __launch_bounds__(256) void k_init_emb(const float* __restrict__ feat,
                                                  float* __restrict__ out) {
    int i = blockIdx.x * 256 + threadIdx.x;           // float4 idx within relation
    int k = blockIdx.y;
    const f4* f = (const f4*)feat;
    f4* o = (f4*)out;
    o[(size_t)k * (NN * DD / 4) + i] = f[i];
}

// ---- precompute rel vectors for all steps 0..3, write final rels to output ----
__global__ __launch_bounds__(256) void k_rels(
    const float* __restrict__ nr, const float* __restrict__ poir,
    const float* __restrict__ sr, const float* __restrict__ dr,
    const float* __restrict__ relW, const float* __restrict__ relb,
    float* __restrict__ rels_all, float* __restrict__ rel_out) {
    __shared__ float cur[4][64];
    int tid = threadIdx.x;
    int k = tid >> 6, j = tid & 63;
    const float* r0 = (k == 0) ? nr : (k == 1) ? poir : (k == 2) ? sr : dr;
    float v = r0[j];
    cur[k][j] = v;
    rels_all[(0 * 4 + k) * 64 + j] = v;
    __syncthreads();
    for (int s = 0; s < 3; ++s) {
        const float* W = relW + s * 4096;   // out[j] = sum_kk cur[kk] * W[j*64+kk]
        float acc = relb[s * 64 + j];
        #pragma unroll 8
        for (int kk = 0; kk < 64; ++kk) acc += cur[k][kk] * W[j * 64 + kk];
        __syncthreads();
        cur[k][j] = acc;
        rels_all[((s + 1) * 4 + k) * 64 + j] = acc;
        __syncthreads();
    }
    rel_out[k * 64 + j] = cur[k][j];
}

// ---- degree (with self-loop) -> dinv ----
__global__ __launch_bounds__(256) void k_deg_init(float* __restrict__ deg) {
    int i = blockIdx.x * 256 + threadIdx.x;
    if (i < 4 * NN) deg[i] = 1.0f;     // self-loop contributes 1
}
__global__ __launch_bounds__(256) void k_deg_count(
    const int* __restrict__ e0, const int* __restrict__ e1,
    const int* __restrict__ e2, const int* __restrict__ e3,
    float* __restrict__ deg) {
    int idx = blockIdx.x * 256 + threadIdx.x;    // over 4*EE (exact)
    int k = idx / EE;
    int e = idx - k * EE;
    const int* ed = (k == 0) ? e0 : (k == 1) ? e1 : (k == 2) ? e2 : e3;
    int dst = ed[EE + e];
    atomicAdd(deg + k * NN + dst, 1.0f);
}
__global__ __launch_bounds__(256) void k_dinv(float* __restrict__ deg) {
    int i = blockIdx.x * 256 + threadIdx.x;
    if (i < 4 * NN) deg[i] = rsqrtf(deg[i]);
}

// ---- h = (emb .* rel) @ W ----
__global__ __launch_bounds__(256) void k_gemm(
    const float* __restrict__ emb, const float* __restrict__ rels,
    const float* __restrict__ W, float* __restrict__ h, int krel0) {
    __shared__ float Wl[4096];
    __shared__ float xl[16][68];     // 68: 16B-aligned rows + bank-conflict-free bcast
    int tid = threadIdx.x;
    int kr = blockIdx.y, ka = krel0 + kr;
    int row0 = blockIdx.x * 16;
    {
        const f4* W4 = (const f4*)W;
        f4* Wl4 = (f4*)Wl;
        Wl4[tid] = W4[tid];
        Wl4[tid + 256] = W4[tid + 256];
        Wl4[tid + 512] = W4[tid + 512];
        Wl4[tid + 768] = W4[tid + 768];
    }
    int rl = tid >> 4, c4 = (tid & 15) * 4;
    {
        f4 xv = *(const f4*)(emb + (size_t)ka * NN * DD + (size_t)(row0 + rl) * DD + c4);
        f4 rv = *(const f4*)(rels + ka * 64 + c4);
        xl[rl][c4 + 0] = xv.x * rv.x;
        xl[rl][c4 + 1] = xv.y * rv.y;
        xl[rl][c4 + 2] = xv.z * rv.z;
        xl[rl][c4 + 3] = xv.w * rv.w;
    }
    __syncthreads();
    float ax = 0.f, ay = 0.f, az = 0.f, aw = 0.f;
    #pragma unroll
    for (int kk = 0; kk < 64; ++kk) {
        float xv = xl[rl][kk];
        const float* wrow = Wl + kk * 64 + c4;
        ax += xv * wrow[0];
        ay += xv * wrow[1];
        az += xv * wrow[2];
        aw += xv * wrow[3];
    }
    f4 o = {ax, ay, az, aw};
    *(f4*)(h + (size_t)kr * NN * DD + (size_t)(row0 + rl) * DD + c4) = o;
}

// ---- agg = bias + self-loop message ----
__global__ __launch_bounds__(256) void k_agg_init(
    const float* __restrict__ h, const float* __restrict__ dinv,
    const float* __restrict__ b, float* __restrict__ agg, int krel0) {
    int i4 = blockIdx.x * 256 + threadIdx.x;   // [0, NN*16)
    int kr = blockIdx.y, ka = krel0 + kr;
    int row = i4 >> 4, c4 = (i4 & 15) * 4;
    float di = dinv[ka * NN + row];
    float nrm = di * di;
    f4 hv = ((const f4*)h)[(size_t)kr * (NN * 16) + i4];
    f4 o;
    o.x = b[c4 + 0] + hv.x * nrm;
    o.y = b[c4 + 1] + hv.y * nrm;
    o.z = b[c4 + 2] + hv.z * nrm;
    o.w = b[c4 + 3] + hv.w * nrm;
    ((f4*)agg)[(size_t)kr * (NN * 16) + i4] = o;
}

// ---- edge scatter: one wave per edge, lane = feature ----
__global__ __launch_bounds__(256) void k_scatter(
    const int* __restrict__ e0, const int* __restrict__ e1,
    const int* __restrict__ e2, const int* __restrict__ e3,
    const float* __restrict__ h, const float* __restrict__ dinv,
    float* __restrict__ agg, int krel0, int nrel) {
    int lane = threadIdx.x & 63;
    int wid = (blockIdx.x * 256 + threadIdx.x) >> 6;
    int nw = (gridDim.x * 256) >> 6;
    int total = nrel * EE;
    for (int e = wid; e < total; e += nw) {
        int kr = e / EE;
        int el = e - kr * EE;
        int ka = krel0 + kr;
        const int* ed = (ka == 0) ? e0 : (ka == 1) ? e1 : (ka == 2) ? e2 : e3;
        int src = ed[el], dst = ed[EE + el];
        float nrm = dinv[ka * NN + src] * dinv[ka * NN + dst];
        float v = h[(size_t)kr * NN * DD + (size_t)src * DD + lane] * nrm;
        atomicAdd(agg + (size_t)kr * NN * DD + (size_t)dst * DD + lane, v);
    }
}

// ---- BN column stats (sum, sumsq) via per-wave partials + atomics ----
__global__ __launch_bounds__(256) void k_bnstats(
    const float* __restrict__ agg, float* __restrict__ stats, int krel0) {
    int kr = blockIdx.y, ka = krel0 + kr;
    int col = threadIdx.x & 63;
    int w = threadIdx.x >> 6;
    long r0 = (long)blockIdx.x * 256 + w * 64;
    float s = 0.f, s2 = 0.f;
    size_t base = (size_t)kr * NN * DD;
    for (int i = 0; i < 64; ++i) {
        long r = r0 + i;
        if (r < NN) {
            float v = agg[base + r * DD + col];
            s += v;
            s2 += v * v;
        }
    }
    atomicAdd(stats + ka * 128 + col, s);
    atomicAdd(stats + ka * 128 + 64 + col, s2);
}

// ---- BN apply + leaky relu + residual add into emb ----
__global__ __launch_bounds__(256) void k_bnapply(
    const float* __restrict__ agg, const float* __restrict__ stats,
    const float* __restrict__ gamma, const float* __restrict__ beta,
    float* __restrict__ emb, int krel0) {
    int kr = blockIdx.y, ka = krel0 + kr;
    size_t i = (size_t)blockIdx.x * 256 + threadIdx.x;   // [0, NN*DD)
    int col = (int)(i & 63);
    float mean = stats[ka * 128 + col] * (1.0f / NN);
    float m2 = stats[ka * 128 + 64 + col] * (1.0f / NN);
    float var = m2 - mean * mean;
    float inv = rsqrtf(var + BN_EPS);
    float v = agg[(size_t)kr * NN * DD + i];
    float xn = gamma[col] * (v - mean) * inv + beta[col];
    float ly = xn >= 0.f ? xn : NEG * xn;
    emb[(size_t)ka * NN * DD + i] += ly;
}

// ---- final layer: emb = agg ----
__global__ __launch_bounds__(256) void k_copy(const float* __restrict__ agg,
                                              float* __restrict__ out, int krel0) {
    int i = blockIdx.x * 256 + threadIdx.x;   // float4 idx
    int kr = blockIdx.y, ka = krel0 + kr;
    ((f4*)out)[(size_t)ka * (NN * 16) + i] = ((const f4*)agg)[(size_t)kr * (NN * 16) + i];
}

extern "C" void kernel_launch(void* const* d_in, const int* in_sizes, int n_in,
                              void* d_out, int out_size, void* d_ws, size_t ws_size,
                              hipStream_t stream) {
    const float* feat = (const float*)d_in[0];
    const float* poir = (const float*)d_in[1];
    const float* sr   = (const float*)d_in[2];
    const float* dr   = (const float*)d_in[3];
    const float* nr   = (const float*)d_in[4];
    const int* e_poi  = (const int*)d_in[5];
    const int* e_s    = (const int*)d_in[6];
    const int* e_d    = (const int*)d_in[7];
    const int* e_n    = (const int*)d_in[8];
    const float* gcnW = (const float*)d_in[9];
    const float* gcnb = (const float*)d_in[10];
    const float* bng  = (const float*)d_in[11];
    const float* bnb  = (const float*)d_in[12];
    const float* relW = (const float*)d_in[13];
    const float* relb = (const float*)d_in[14];

    float* out = (float*)d_out;
    float* rel_out = out + (size_t)4 * NN * DD;
    float* ws = (float*)d_ws;
    float* dinv     = ws;             // 4*NN = 200000 floats
    float* rels_all = ws + 200000;    // 4 steps * 4 rel * 64 = 1024
    float* stats    = ws + 201024;    // 4 * 128 = 512
    float* bufs     = ws + 201536;

    size_t need = ((size_t)201536 + (size_t)8 * NN * DD) * sizeof(float);
    int g = (ws_size >= need) ? 4 : 1;
    float* h   = bufs;
    float* agg = bufs + (size_t)g * NN * DD;

    // relation order n, poi, s, d (matches reference iteration & output order)
    const int* E0 = e_n;  const int* E1 = e_poi;
    const int* E2 = e_s;  const int* E3 = e_d;

    k_init_emb<<<dim3(3125, 4), 256, 0, stream>>>(feat, out);
    k_rels<<<1, 256, 0, stream>>>(nr, poir, sr, dr, relW, relb, rels_all, rel_out);
    k_deg_init<<<(4 * NN + 255) / 256, 256, 0, stream>>>(dinv);
    k_deg_count<<<(4 * EE) / 256, 256, 0, stream>>>(E0, E1, E2, E3, dinv);
    k_dinv<<<(4 * NN + 255) / 256, 256, 0, stream>>>(dinv);

    for (int l = 0; l < 3; ++l) {
        const float* Wl = gcnW + l * 4096;
        const float* bl = gcnb + l * 64;
        const float* rl = rels_all + l * 256;
        if (l < 2) hipMemsetAsync(stats, 0, 512 * sizeof(float), stream);
        for (int k0 = 0; k0 < 4; k0 += g) {
            k_gemm<<<dim3(3125, g), 256, 0, stream>>>(out, rl, Wl, h, k0);
            k_agg_init<<<dim3(3125, g), 256, 0, stream>>>(h, dinv, bl, agg, k0);
            k_scatter<<<dim3(4096), 256, 0, stream>>>(E0, E1, E2, E3, h, dinv, agg, k0, g);
            if (l < 2) {
                k_bnstats<<<dim3(196, g), 256, 0, stream>>>(agg, stats, k0);
                k_bnapply<<<dim3(12500, g), 256, 0, stream>>>(agg, stats, bng + l * 64, bnb + l * 64, out, k0);
            } else {
                k_copy<<<dim3(3125, g), 256, 0, stream>>>(agg, out, k0);
            }
        }
    }
}

// Round 2
// 1252.202 us; speedup vs baseline: 2.0840x; 2.0840x over previous
//
#include <hip/hip_runtime.h>

#define NN 50000
#define DD 64
#define EE 800000
#define BN_EPS 1e-5f
#define NEG 0.01f

typedef float4 f4;

// ---- init embeddings: 4 copies of features into d_out ----
__global__ __launch_bounds__(256) void k_init_emb(const float* __restrict__ feat,
                                                  float* __restrict__ out) {
    int i = blockIdx.x * 256 + threadIdx.x;           // float4 idx within relation
    int k = blockIdx.y;
    const f4* f = (const f4*)feat;
    f4* o = (f4*)out;
    o[(size_t)k * (NN * DD / 4) + i] = f[i];
}

// ---- precompute rel vectors for all steps 0..3, write final rels to output ----
__global__ __launch_bounds__(256) void k_rels(
    const float* __restrict__ nr, const float* __restrict__ poir,
    const float* __restrict__ sr, const float* __restrict__ dr,
    const float* __restrict__ relW, const float* __restrict__ relb,
    float* __restrict__ rels_all, float* __restrict__ rel_out) {
    __shared__ float cur[4][64];
    int tid = threadIdx.x;
    int k = tid >> 6, j = tid & 63;
    const float* r0 = (k == 0) ? nr : (k == 1) ? poir : (k == 2) ? sr : dr;
    float v = r0[j];
    cur[k][j] = v;
    rels_all[(0 * 4 + k) * 64 + j] = v;
    __syncthreads();
    for (int s = 0; s < 3; ++s) {
        const float* W = relW + s * 4096;   // out[j] = sum_kk cur[kk] * W[j*64+kk]
        float acc = relb[s * 64 + j];
        #pragma unroll 8
        for (int kk = 0; kk < 64; ++kk) acc += cur[k][kk] * W[j * 64 + kk];
        __syncthreads();
        cur[k][j] = acc;
        rels_all[((s + 1) * 4 + k) * 64 + j] = acc;
        __syncthreads();
    }
    rel_out[k * 64 + j] = cur[k][j];
}

// ---- int degree count (real in-edges only, no self-loop) ----
__global__ __launch_bounds__(256) void k_deg_count_i(
    const int* __restrict__ e0, const int* __restrict__ e1,
    const int* __restrict__ e2, const int* __restrict__ e3,
    int* __restrict__ ideg) {
    int idx = blockIdx.x * 256 + threadIdx.x;    // over 4*EE (exact)
    int k = idx / EE;
    int e = idx - k * EE;
    const int* ed = (k == 0) ? e0 : (k == 1) ? e1 : (k == 2) ? e2 : e3;
    int dst = ed[EE + e];
    atomicAdd(ideg + k * NN + dst, 1);
}

// ---- prefix-sum step A: per-block exclusive scan + block sums ----
__global__ __launch_bounds__(256) void k_scanA(const int* __restrict__ ideg,
                                               int* __restrict__ off,
                                               int* __restrict__ bsum) {
    __shared__ int s[256];
    int tid = threadIdx.x;
    int i = blockIdx.x * 256 + tid;
    int v = (i < 4 * NN) ? ideg[i] : 0;
    s[tid] = v;
    __syncthreads();
    for (int d = 1; d < 256; d <<= 1) {
        int t = (tid >= d) ? s[tid - d] : 0;
        __syncthreads();
        s[tid] += t;
        __syncthreads();
    }
    if (i < 4 * NN) off[i] = s[tid] - v;     // exclusive within block
    if (tid == 255) bsum[blockIdx.x] = s[255];
}

// ---- prefix-sum step B: scan the 782 block sums in place (exclusive) ----
__global__ __launch_bounds__(256) void k_scanB(int* __restrict__ bsum, int nb) {
    __shared__ int s[256];
    __shared__ int carry;
    int tid = threadIdx.x;
    if (tid == 0) carry = 0;
    __syncthreads();
    for (int base = 0; base < nb; base += 256) {
        int i = base + tid;
        int v = (i < nb) ? bsum[i] : 0;
        s[tid] = v;
        __syncthreads();
        for (int d = 1; d < 256; d <<= 1) {
            int t = (tid >= d) ? s[tid - d] : 0;
            __syncthreads();
            s[tid] += t;
            __syncthreads();
        }
        int total = s[255];
        int c = carry;
        if (i < nb) bsum[i] = s[tid] - v + c;
        __syncthreads();
        if (tid == 0) carry = c + total;
        __syncthreads();
    }
}

// ---- prefix-sum step C: add block offsets; set sentinel ----
__global__ __launch_bounds__(256) void k_scanC(int* __restrict__ off,
                                               const int* __restrict__ bsum) {
    int i = blockIdx.x * 256 + threadIdx.x;
    if (i < 4 * NN) off[i] += bsum[blockIdx.x];
    if (i == 0) off[4 * NN] = 4 * EE;
}

// ---- dinv = rsqrt(deg+1); zero fill cursors ----
__global__ __launch_bounds__(256) void k_dinv(const int* __restrict__ ideg,
                                              float* __restrict__ dinv,
                                              int* __restrict__ cur) {
    int i = blockIdx.x * 256 + threadIdx.x;
    if (i < 4 * NN) {
        dinv[i] = rsqrtf((float)(ideg[i] + 1));
        cur[i] = 0;
    }
}

// ---- CSR fill: csr[slot] = {src, norm} ----
__global__ __launch_bounds__(256) void k_fill(
    const int* __restrict__ e0, const int* __restrict__ e1,
    const int* __restrict__ e2, const int* __restrict__ e3,
    const int* __restrict__ off, int* __restrict__ cur,
    const float* __restrict__ dinv, int2* __restrict__ csr) {
    int idx = blockIdx.x * 256 + threadIdx.x;    // over 4*EE (exact)
    int k = idx / EE;
    int e = idx - k * EE;
    const int* ed = (k == 0) ? e0 : (k == 1) ? e1 : (k == 2) ? e2 : e3;
    int src = ed[e], dst = ed[EE + e];
    int p = atomicAdd(cur + k * NN + dst, 1);
    int slot = off[k * NN + dst] + p;
    float nrm = dinv[k * NN + src] * dinv[k * NN + dst];
    csr[slot] = make_int2(src, __float_as_int(nrm));
}

// ---- h = (emb .* rel) @ W ----
__global__ __launch_bounds__(256) void k_gemm(
    const float* __restrict__ emb, const float* __restrict__ rels,
    const float* __restrict__ W, float* __restrict__ h) {
    __shared__ float Wl[4096];
    __shared__ float xl[16][68];
    int tid = threadIdx.x;
    int ka = blockIdx.y;
    int row0 = blockIdx.x * 16;
    {
        const f4* W4 = (const f4*)W;
        f4* Wl4 = (f4*)Wl;
        Wl4[tid] = W4[tid];
        Wl4[tid + 256] = W4[tid + 256];
        Wl4[tid + 512] = W4[tid + 512];
        Wl4[tid + 768] = W4[tid + 768];
    }
    int rl = tid >> 4, c4 = (tid & 15) * 4;
    {
        f4 xv = *(const f4*)(emb + (size_t)ka * NN * DD + (size_t)(row0 + rl) * DD + c4);
        f4 rv = *(const f4*)(rels + ka * 64 + c4);
        xl[rl][c4 + 0] = xv.x * rv.x;
        xl[rl][c4 + 1] = xv.y * rv.y;
        xl[rl][c4 + 2] = xv.z * rv.z;
        xl[rl][c4 + 3] = xv.w * rv.w;
    }
    __syncthreads();
    float ax = 0.f, ay = 0.f, az = 0.f, aw = 0.f;
    #pragma unroll
    for (int kk = 0; kk < 64; ++kk) {
        float xv = xl[rl][kk];
        const float* wrow = Wl + kk * 64 + c4;
        ax += xv * wrow[0];
        ay += xv * wrow[1];
        az += xv * wrow[2];
        aw += xv * wrow[3];
    }
    f4 o = {ax, ay, az, aw};
    *(f4*)(h + (size_t)ka * NN * DD + (size_t)(row0 + rl) * DD + c4) = o;
}

// ---- gather: one wave per dst node; acc = b + selfloop + sum_in h[src]*norm ----
__global__ __launch_bounds__(256) void k_gather(
    const float* __restrict__ h, const int2* __restrict__ csr,
    const int* __restrict__ off, const float* __restrict__ dinv,
    const float* __restrict__ b, float* __restrict__ dstbuf) {
    int lane = threadIdx.x & 63;
    int dst = blockIdx.x * 4 + (threadIdx.x >> 6);
    int ka = blockIdx.y;
    int idx = ka * NN + dst;
    int s0 = off[idx], s1 = off[idx + 1];
    float di = dinv[idx];
    size_t hbase = (size_t)ka * NN * DD;
    float acc = b[lane] + h[hbase + (size_t)dst * DD + lane] * di * di;
    int i = s0;
    for (; i + 1 < s1; i += 2) {
        int2 a = csr[i];
        int2 c = csr[i + 1];
        float va = h[hbase + (size_t)a.x * DD + lane];
        float vc = h[hbase + (size_t)c.x * DD + lane];
        acc += va * __int_as_float(a.y);
        acc += vc * __int_as_float(c.y);
    }
    if (i < s1) {
        int2 a = csr[i];
        acc += h[hbase + (size_t)a.x * DD + lane] * __int_as_float(a.y);
    }
    dstbuf[hbase + (size_t)dst * DD + lane] = acc;
}

// ---- BN column stats (sum, sumsq) via per-wave partials + atomics ----
__global__ __launch_bounds__(256) void k_bnstats(
    const float* __restrict__ agg, float* __restrict__ stats) {
    int ka = blockIdx.y;
    int col = threadIdx.x & 63;
    int w = threadIdx.x >> 6;
    long r0 = (long)blockIdx.x * 256 + w * 64;
    float s = 0.f, s2 = 0.f;
    size_t base = (size_t)ka * NN * DD;
    for (int i = 0; i < 64; ++i) {
        long r = r0 + i;
        if (r < NN) {
            float v = agg[base + r * DD + col];
            s += v;
            s2 += v * v;
        }
    }
    atomicAdd(stats + ka * 128 + col, s);
    atomicAdd(stats + ka * 128 + 64 + col, s2);
}

// ---- BN apply + leaky relu + residual add into emb ----
__global__ __launch_bounds__(256) void k_bnapply(
    const float* __restrict__ agg, const float* __restrict__ stats,
    const float* __restrict__ gamma, const float* __restrict__ beta,
    float* __restrict__ emb) {
    int ka = blockIdx.y;
    size_t i = (size_t)blockIdx.x * 256 + threadIdx.x;   // [0, NN*DD)
    int col = (int)(i & 63);
    float mean = stats[ka * 128 + col] * (1.0f / NN);
    float m2 = stats[ka * 128 + 64 + col] * (1.0f / NN);
    float var = m2 - mean * mean;
    float inv = rsqrtf(var + BN_EPS);
    float v = agg[(size_t)ka * NN * DD + i];
    float xn = gamma[col] * (v - mean) * inv + beta[col];
    float ly = xn >= 0.f ? xn : NEG * xn;
    emb[(size_t)ka * NN * DD + i] += ly;
}

extern "C" void kernel_launch(void* const* d_in, const int* in_sizes, int n_in,
                              void* d_out, int out_size, void* d_ws, size_t ws_size,
                              hipStream_t stream) {
    const float* feat = (const float*)d_in[0];
    const float* poir = (const float*)d_in[1];
    const float* sr   = (const float*)d_in[2];
    const float* dr   = (const float*)d_in[3];
    const float* nr   = (const float*)d_in[4];
    const int* e_poi  = (const int*)d_in[5];
    const int* e_s    = (const int*)d_in[6];
    const int* e_d    = (const int*)d_in[7];
    const int* e_n    = (const int*)d_in[8];
    const float* gcnW = (const float*)d_in[9];
    const float* gcnb = (const float*)d_in[10];
    const float* bng  = (const float*)d_in[11];
    const float* bnb  = (const float*)d_in[12];
    const float* relW = (const float*)d_in[13];
    const float* relb = (const float*)d_in[14];

    float* out = (float*)d_out;
    float* rel_out = out + (size_t)4 * NN * DD;
    float* ws = (float*)d_ws;

    float* dinv     = ws;                      // 200000
    float* rels_all = ws + 200000;             // 1024
    float* stats    = ws + 201024;             // 512
    int*   ideg     = (int*)(ws + 201536);     // 200000
    int*   off      = ideg + 200000;           // 200001
    int*   curp     = off + 200001;            // 200000
    int*   bsum     = curp + 200000;           // 800
    // pad to 8-byte alignment for int2
    size_t csr_word = 201536 + 200000 + 200001 + 200000 + 800;
    if (csr_word & 1) csr_word++;
    int2*  csr      = (int2*)(ws + csr_word);  // 4*EE int2 = 6.4M words
    float* h        = ws + csr_word + (size_t)8 * EE;   // 12.8M floats
    float* agg      = h + (size_t)4 * NN * DD;          // 12.8M floats

    const int* E0 = e_n;  const int* E1 = e_poi;
    const int* E2 = e_s;  const int* E3 = e_d;

    const int NB = (4 * NN + 255) / 256;   // 782

    k_init_emb<<<dim3(3125, 4), 256, 0, stream>>>(feat, out);
    k_rels<<<1, 256, 0, stream>>>(nr, poir, sr, dr, relW, relb, rels_all, rel_out);
    hipMemsetAsync(ideg, 0, 4 * NN * sizeof(int), stream);
    k_deg_count_i<<<(4 * EE) / 256, 256, 0, stream>>>(E0, E1, E2, E3, ideg);
    k_scanA<<<NB, 256, 0, stream>>>(ideg, off, bsum);
    k_scanB<<<1, 256, 0, stream>>>(bsum, NB);
    k_scanC<<<NB, 256, 0, stream>>>(off, bsum);
    k_dinv<<<NB, 256, 0, stream>>>(ideg, dinv, curp);
    k_fill<<<(4 * EE) / 256, 256, 0, stream>>>(E0, E1, E2, E3, off, curp, dinv, csr);

    for (int l = 0; l < 3; ++l) {
        const float* Wl = gcnW + l * 4096;
        const float* bl = gcnb + l * 64;
        const float* rl = rels_all + l * 256;
        k_gemm<<<dim3(3125, 4), 256, 0, stream>>>(out, rl, Wl, h);
        if (l < 2) {
            hipMemsetAsync(stats, 0, 512 * sizeof(float), stream);
            k_gather<<<dim3(12500, 4), 256, 0, stream>>>(h, csr, off, dinv, bl, agg);
            k_bnstats<<<dim3(196, 4), 256, 0, stream>>>(agg, stats);
            k_bnapply<<<dim3(12500, 4), 256, 0, stream>>>(agg, stats, bng + l * 64, bnb + l * 64, out);
        } else {
            k_gather<<<dim3(12500, 4), 256, 0, stream>>>(h, csr, off, dinv, bl, out);
        }
    }
}

// Round 3
// 1019.156 us; speedup vs baseline: 2.5606x; 1.2287x over previous
//
#include <hip/hip_runtime.h>

#define NN 50000
#define DD 64
#define EE 800000
#define BN_EPS 1e-5f
#define NEG 0.01f

typedef float4 f4;

__device__ __forceinline__ float b2f(unsigned short u) {
    return __uint_as_float(((unsigned)u) << 16);
}
__device__ __forceinline__ unsigned short f2b(float x) {
    unsigned u = __float_as_uint(x);
    u += 0x7fffu + ((u >> 16) & 1u);   // RNE
    return (unsigned short)(u >> 16);
}

// ---- precompute rel vectors for all steps 0..3, write final rels to output ----
__global__ __launch_bounds__(256) void k_rels(
    const float* __restrict__ nr, const float* __restrict__ poir,
    const float* __restrict__ sr, const float* __restrict__ dr,
    const float* __restrict__ relW, const float* __restrict__ relb,
    float* __restrict__ rels_all, float* __restrict__ rel_out) {
    __shared__ float cur[4][64];
    int tid = threadIdx.x;
    int k = tid >> 6, j = tid & 63;
    const float* r0 = (k == 0) ? nr : (k == 1) ? poir : (k == 2) ? sr : dr;
    float v = r0[j];
    cur[k][j] = v;
    rels_all[(0 * 4 + k) * 64 + j] = v;
    __syncthreads();
    for (int s = 0; s < 3; ++s) {
        const float* W = relW + s * 4096;
        float acc = relb[s * 64 + j];
        #pragma unroll 8
        for (int kk = 0; kk < 64; ++kk) acc += cur[k][kk] * W[j * 64 + kk];
        __syncthreads();
        cur[k][j] = acc;
        rels_all[((s + 1) * 4 + k) * 64 + j] = acc;
        __syncthreads();
    }
    rel_out[k * 64 + j] = cur[k][j];
}

// ---- int degree count ----
__global__ __launch_bounds__(256) void k_deg_count_i(
    const int* __restrict__ e0, const int* __restrict__ e1,
    const int* __restrict__ e2, const int* __restrict__ e3,
    int* __restrict__ ideg) {
    int idx = blockIdx.x * 256 + threadIdx.x;
    int k = idx / EE;
    int e = idx - k * EE;
    const int* ed = (k == 0) ? e0 : (k == 1) ? e1 : (k == 2) ? e2 : e3;
    int dst = ed[EE + e];
    atomicAdd(ideg + k * NN + dst, 1);
}

// ---- prefix-sum A: per-block exclusive scan + block sums ----
__global__ __launch_bounds__(256) void k_scanA(const int* __restrict__ ideg,
                                               int* __restrict__ off,
                                               int* __restrict__ bsum) {
    __shared__ int s[256];
    int tid = threadIdx.x;
    int i = blockIdx.x * 256 + tid;
    int v = (i < 4 * NN) ? ideg[i] : 0;
    s[tid] = v;
    __syncthreads();
    for (int d = 1; d < 256; d <<= 1) {
        int t = (tid >= d) ? s[tid - d] : 0;
        __syncthreads();
        s[tid] += t;
        __syncthreads();
    }
    if (i < 4 * NN) off[i] = s[tid] - v;
    if (tid == 255) bsum[blockIdx.x] = s[255];
}

// ---- prefix-sum B: scan block sums in place ----
__global__ __launch_bounds__(256) void k_scanB(int* __restrict__ bsum, int nb) {
    __shared__ int s[256];
    __shared__ int carry;
    int tid = threadIdx.x;
    if (tid == 0) carry = 0;
    __syncthreads();
    for (int base = 0; base < nb; base += 256) {
        int i = base + tid;
        int v = (i < nb) ? bsum[i] : 0;
        s[tid] = v;
        __syncthreads();
        for (int d = 1; d < 256; d <<= 1) {
            int t = (tid >= d) ? s[tid - d] : 0;
            __syncthreads();
            s[tid] += t;
            __syncthreads();
        }
        int total = s[255];
        int c = carry;
        if (i < nb) bsum[i] = s[tid] - v + c;
        __syncthreads();
        if (tid == 0) carry = c + total;
        __syncthreads();
    }
}

// ---- prefix-sum C: add block offsets; sentinel ----
__global__ __launch_bounds__(256) void k_scanC(int* __restrict__ off,
                                               const int* __restrict__ bsum) {
    int i = blockIdx.x * 256 + threadIdx.x;
    if (i < 4 * NN) off[i] += bsum[blockIdx.x];
    if (i == 0) off[4 * NN] = 4 * EE;
}

// ---- dinv = rsqrt(deg+1); zero fill cursors ----
__global__ __launch_bounds__(256) void k_dinv(const int* __restrict__ ideg,
                                              float* __restrict__ dinv,
                                              int* __restrict__ cur) {
    int i = blockIdx.x * 256 + threadIdx.x;
    if (i < 4 * NN) {
        dinv[i] = rsqrtf((float)(ideg[i] + 1));
        cur[i] = 0;
    }
}

// ---- CSR fill: src index only ----
__global__ __launch_bounds__(256) void k_fill(
    const int* __restrict__ e0, const int* __restrict__ e1,
    const int* __restrict__ e2, const int* __restrict__ e3,
    const int* __restrict__ off, int* __restrict__ cur,
    int* __restrict__ csr) {
    int idx = blockIdx.x * 256 + threadIdx.x;
    int k = idx / EE;
    int e = idx - k * EE;
    const int* ed = (k == 0) ? e0 : (k == 1) ? e1 : (k == 2) ? e2 : e3;
    int src = ed[e], dst = ed[EE + e];
    int p = atomicAdd(cur + k * NN + dst, 1);
    csr[off[k * NN + dst] + p] = src;
}

// ---- fused GEMM: [optional BN+leaky+residual] then h_bf = (e .* rel) @ W ----
// mode 0: prev=feat (shared), no BN.  mode 1: prev=feat, BN(agg), write e1.
// mode 2: prev=e1, BN(agg), no write.
__global__ __launch_bounds__(256) void k_gemm(
    const float* __restrict__ prevbuf, size_t prev_ka_stride,
    const float* __restrict__ agg, const float* __restrict__ stats,
    const float* __restrict__ gamma, const float* __restrict__ beta,
    const float* __restrict__ rels, const float* __restrict__ W,
    float* __restrict__ e1, unsigned short* __restrict__ h_bf, int mode) {
    __shared__ float Wl[4096];
    __shared__ float xl[16][68];
    int tid = threadIdx.x;
    int ka = blockIdx.y;
    int row0 = blockIdx.x * 16;
    {
        const f4* W4 = (const f4*)W;
        f4* Wl4 = (f4*)Wl;
        Wl4[tid] = W4[tid];
        Wl4[tid + 256] = W4[tid + 256];
        Wl4[tid + 512] = W4[tid + 512];
        Wl4[tid + 768] = W4[tid + 768];
    }
    int rl = tid >> 4, c4 = (tid & 15) * 4;
    int row = row0 + rl;
    size_t kabase = (size_t)ka * NN * DD;
    {
        f4 pv = *(const f4*)(prevbuf + (size_t)ka * prev_ka_stride + (size_t)row * DD + c4);
        if (mode > 0) {
            f4 av = *(const f4*)(agg + kabase + (size_t)row * DD + c4);
            float* a = &av.x;
            float* p = &pv.x;
            #pragma unroll
            for (int j = 0; j < 4; ++j) {
                int col = c4 + j;
                float mean = stats[ka * 128 + col] * (1.0f / NN);
                float m2 = stats[ka * 128 + 64 + col] * (1.0f / NN);
                float inv = rsqrtf(m2 - mean * mean + BN_EPS);
                float xn = gamma[col] * (a[j] - mean) * inv + beta[col];
                p[j] += (xn >= 0.f) ? xn : NEG * xn;
            }
            if (mode == 1) *(f4*)(e1 + kabase + (size_t)row * DD + c4) = pv;
        }
        f4 rv = *(const f4*)(rels + ka * 64 + c4);
        xl[rl][c4 + 0] = pv.x * rv.x;
        xl[rl][c4 + 1] = pv.y * rv.y;
        xl[rl][c4 + 2] = pv.z * rv.z;
        xl[rl][c4 + 3] = pv.w * rv.w;
    }
    __syncthreads();
    float ax = 0.f, ay = 0.f, az = 0.f, aw = 0.f;
    #pragma unroll
    for (int kk = 0; kk < 64; ++kk) {
        float xv = xl[rl][kk];
        const float* wrow = Wl + kk * 64 + c4;
        ax += xv * wrow[0];
        ay += xv * wrow[1];
        az += xv * wrow[2];
        aw += xv * wrow[3];
    }
    ushort4 o;
    o.x = f2b(ax); o.y = f2b(ay); o.z = f2b(az); o.w = f2b(aw);
    *(ushort4*)(h_bf + kabase + (size_t)row * DD + c4) = o;
}

// ---- gather: one wave per dst; acc = b + selfloop + sum h_bf[src]*norm ----
__global__ __launch_bounds__(256) void k_gather(
    const unsigned short* __restrict__ h_bf, const int* __restrict__ csr,
    const int* __restrict__ off, const float* __restrict__ dinv,
    const float* __restrict__ b, float* __restrict__ dstbuf) {
    int lane = threadIdx.x & 63;
    int dst = blockIdx.x * 4 + (threadIdx.x >> 6);
    int ka = blockIdx.y;
    int idx = ka * NN + dst;
    int s0 = off[idx], s1 = off[idx + 1];
    float di = dinv[idx];
    const float* dk = dinv + ka * NN;
    const unsigned short* hb = h_bf + (size_t)ka * NN * DD;
    float acc = b[lane] + b2f(hb[(size_t)dst * DD + lane]) * di * di;
    int i = s0;
    for (; i + 3 < s1; i += 4) {
        int sa = csr[i], sb = csr[i + 1], sc = csr[i + 2], sd = csr[i + 3];
        float na = dk[sa], nb2 = dk[sb], nc = dk[sc], nd = dk[sd];
        float va = b2f(hb[(size_t)sa * DD + lane]);
        float vb = b2f(hb[(size_t)sb * DD + lane]);
        float vc = b2f(hb[(size_t)sc * DD + lane]);
        float vd = b2f(hb[(size_t)sd * DD + lane]);
        acc += va * (na * di) + vb * (nb2 * di) + vc * (nc * di) + vd * (nd * di);
    }
    for (; i < s1; ++i) {
        int sa = csr[i];
        acc += b2f(hb[(size_t)sa * DD + lane]) * (dk[sa] * di);
    }
    dstbuf[(size_t)ka * NN * DD + (size_t)dst * DD + lane] = acc;
}

// ---- BN column stats ----
__global__ __launch_bounds__(256) void k_bnstats(
    const float* __restrict__ agg, float* __restrict__ stats) {
    int ka = blockIdx.y;
    int col = threadIdx.x & 63;
    int w = threadIdx.x >> 6;
    long r0 = (long)blockIdx.x * 256 + w * 64;
    float s = 0.f, s2 = 0.f;
    size_t base = (size_t)ka * NN * DD;
    for (int i = 0; i < 64; ++i) {
        long r = r0 + i;
        if (r < NN) {
            float v = agg[base + r * DD + col];
            s += v;
            s2 += v * v;
        }
    }
    atomicAdd(stats + ka * 128 + col, s);
    atomicAdd(stats + ka * 128 + 64 + col, s2);
}

extern "C" void kernel_launch(void* const* d_in, const int* in_sizes, int n_in,
                              void* d_out, int out_size, void* d_ws, size_t ws_size,
                              hipStream_t stream) {
    const float* feat = (const float*)d_in[0];
    const float* poir = (const float*)d_in[1];
    const float* sr   = (const float*)d_in[2];
    const float* dr   = (const float*)d_in[3];
    const float* nr   = (const float*)d_in[4];
    const int* e_poi  = (const int*)d_in[5];
    const int* e_s    = (const int*)d_in[6];
    const int* e_d    = (const int*)d_in[7];
    const int* e_n    = (const int*)d_in[8];
    const float* gcnW = (const float*)d_in[9];
    const float* gcnb = (const float*)d_in[10];
    const float* bng  = (const float*)d_in[11];
    const float* bnb  = (const float*)d_in[12];
    const float* relW = (const float*)d_in[13];
    const float* relb = (const float*)d_in[14];

    float* out = (float*)d_out;
    float* rel_out = out + (size_t)4 * NN * DD;
    float* ws = (float*)d_ws;

    float* dinv     = ws;                        // 200000
    float* rels_all = ws + 200000;               // 1024
    float* stats    = ws + 201024;               // 512
    int*   ideg     = (int*)(ws + 201536);       // 200000
    int*   off      = ideg + 200000;             // 200001
    int*   bsum     = off + 200001;              // 800
    int*   csr      = bsum + 800;                // 3.2M  (starts at word 602337+800... word-exact below)
    // compute word offsets explicitly
    size_t w_csr  = 201536 + 200000 + 200001 + 800;          // 602337... (int region)
    csr = (int*)(ws + w_csr);
    size_t w_hbf  = w_csr + (size_t)4 * EE;                  // + 3.2M words
    unsigned short* h_bf = (unsigned short*)(ws + w_hbf);    // 6.4M ushort = 3.2M words
    size_t w_agg  = w_hbf + (size_t)4 * NN * DD / 2;
    float* agg = ws + w_agg;                                 // 12.8M
    size_t w_e1   = w_agg + (size_t)4 * NN * DD;
    float* e1 = ws + w_e1;                                   // 12.8M
    int* curp = ideg;  // reuse ideg as cursor after dinv computed? NO - need separate
    // use a separate small cursor region after e1
    curp = (int*)(ws + w_e1 + (size_t)4 * NN * DD);          // 200000 ints

    const int* E0 = e_n;  const int* E1 = e_poi;
    const int* E2 = e_s;  const int* E3 = e_d;
    const int NB = (4 * NN + 255) / 256;   // 782

    k_rels<<<1, 256, 0, stream>>>(nr, poir, sr, dr, relW, relb, rels_all, rel_out);
    hipMemsetAsync(ideg, 0, 4 * NN * sizeof(int), stream);
    k_deg_count_i<<<(4 * EE) / 256, 256, 0, stream>>>(E0, E1, E2, E3, ideg);
    k_scanA<<<NB, 256, 0, stream>>>(ideg, off, bsum);
    k_scanB<<<1, 256, 0, stream>>>(bsum, NB);
    k_scanC<<<NB, 256, 0, stream>>>(off, bsum);
    k_dinv<<<NB, 256, 0, stream>>>(ideg, dinv, curp);
    k_fill<<<(4 * EE) / 256, 256, 0, stream>>>(E0, E1, E2, E3, off, curp, csr);

    for (int l = 0; l < 3; ++l) {
        const float* Wl = gcnW + l * 4096;
        const float* bl = gcnb + l * 64;
        const float* rl = rels_all + l * 256;
        if (l == 0) {
            k_gemm<<<dim3(3125, 4), 256, 0, stream>>>(
                feat, (size_t)0, nullptr, nullptr, nullptr, nullptr,
                rl, Wl, nullptr, h_bf, 0);
        } else if (l == 1) {
            k_gemm<<<dim3(3125, 4), 256, 0, stream>>>(
                feat, (size_t)0, agg, stats, bng + 0 * 64, bnb + 0 * 64,
                rl, Wl, e1, h_bf, 1);
        } else {
            k_gemm<<<dim3(3125, 4), 256, 0, stream>>>(
                e1, (size_t)(NN * DD), agg, stats, bng + 1 * 64, bnb + 1 * 64,
                rl, Wl, nullptr, h_bf, 2);
        }
        if (l < 2) {
            k_gather<<<dim3(12500, 4), 256, 0, stream>>>(h_bf, csr, off, dinv, bl, agg);
            hipMemsetAsync(stats, 0, 512 * sizeof(float), stream);
            k_bnstats<<<dim3(196, 4), 256, 0, stream>>>(agg, stats);
        } else {
            k_gather<<<dim3(12500, 4), 256, 0, stream>>>(h_bf, csr, off, dinv, bl, out);
        }
    }
}